// Round 7
// baseline (839.869 us; speedup 1.0000x reference)
//
#include <hip/hip_runtime.h>
#include <hip/hip_bf16.h>
#include <stdint.h>

#define HH   1024
#define FF   1024
#define NE   32
#define NK   4
#define CAP  256

typedef __bf16 bf16x8 __attribute__((ext_vector_type(8)));
typedef __bf16 bf16x4 __attribute__((ext_vector_type(4)));
typedef __bf16 bf16x2 __attribute__((ext_vector_type(2)));
typedef float  f32x4v __attribute__((ext_vector_type(4)));

// ---------------- workspace layout (bytes) ----------------
#define OFF_TOK 1024        // 32*256*4 = 32 KiB
#define OFF_WGT 33792       // 32 KiB
#define OFF_ES  66560       // 16 KiB (packed e<<16|pos per token,k)
#define OFF_RW  82944       // 16 KiB (routing weight per token,k)
#define OFF_T   131072      // 2 MiB  bf16 t
#define OFF_H   2228224     // 16 MiB bf16 h (mlp1 out)
#define OFF_H2  19005440    // 16 MiB bf16 h2 (mlp2 out)

// zero cnt + FULL tok/wgt tables so slots >= Me read token 0 with weight 0
// -> mlp kernels are branch-free over all 256 slots.
__global__ __launch_bounds__(256) void k_zero(
    int* __restrict__ cnt, int* __restrict__ tok, float* __restrict__ wgt)
{
    const int i = blockIdx.x * 256 + threadIdx.x;
    if (i < NE) cnt[i] = 0;
    if (i < NE * CAP) { tok[i] = 0; wgt[i] = 0.f; }
}

// ---------------- router: rmsnorm + gate + top4 + lists ----------------
__global__ __launch_bounds__(256) void k_router(
    const float* __restrict__ x, const float* __restrict__ nscale,
    const float* __restrict__ gw, const float* __restrict__ gb,
    __bf16* __restrict__ tbf, int* __restrict__ cnt,
    int* __restrict__ tok, float* __restrict__ wgt,
    int* __restrict__ res, float* __restrict__ rw)
{
    const int t = blockIdx.x, tid = threadIdx.x;
    __shared__ float tl[HH];
    __shared__ float red[4];
    __shared__ float logits[NE];

    float4 xv = ((const float4*)(x + (size_t)t * HH))[tid];
    float ss = xv.x * xv.x + xv.y * xv.y + xv.z * xv.z + xv.w * xv.w;
    #pragma unroll
    for (int o = 32; o; o >>= 1) ss += __shfl_xor(ss, o);
    if ((tid & 63) == 0) red[tid >> 6] = ss;
    __syncthreads();
    const float mean = (red[0] + red[1] + red[2] + red[3]) * (1.0f / HH);
    const float r = rsqrtf(mean + 1e-5f);
    float4 sc = ((const float4*)nscale)[tid];
    float4 tv;
    tv.x = xv.x * r * sc.x; tv.y = xv.y * r * sc.y;
    tv.z = xv.z * r * sc.z; tv.w = xv.w * r * sc.w;

    ((float4*)tl)[tid] = tv;
    bf16x4 pv = { (__bf16)tv.x, (__bf16)tv.y, (__bf16)tv.z, (__bf16)tv.w };
    *(bf16x4*)(tbf + (size_t)t * HH + tid * 4) = pv;
    __syncthreads();

    const int e = tid >> 3, q = tid & 7;
    const float4* gr = (const float4*)(gw + e * HH + q * 128);
    const float4* tr = (const float4*)(tl + q * 128);
    float s = 0.f;
    #pragma unroll 8
    for (int j = 0; j < 32; ++j) {
        float4 g = gr[j], v = tr[j];
        s += g.x * v.x + g.y * v.y + g.z * v.z + g.w * v.w;
    }
    s += __shfl_xor(s, 1); s += __shfl_xor(s, 2); s += __shfl_xor(s, 4);
    if (q == 0) logits[e] = s + gb[e];
    __syncthreads();

    if (tid == 0) {
        float v[NK]; int id[NK]; unsigned used = 0;
        for (int k = 0; k < NK; ++k) {
            float best = -1e30f; int bi = 0;
            for (int ee = 0; ee < NE; ++ee)
                if (!((used >> ee) & 1u) && logits[ee] > best) { best = logits[ee]; bi = ee; }
            used |= 1u << bi; v[k] = best; id[k] = bi;
        }
        float ex[NK], se = 0.f;
        for (int k = 0; k < NK; ++k) { ex[k] = __expf(v[k] - v[0]); se += ex[k]; }
        const float inv = 1.0f / se;
        for (int k = 0; k < NK; ++k) {
            const float wk = ex[k] * inv;
            int pos = atomicAdd(&cnt[id[k]], 1);
            if (pos < CAP) {
                tok[id[k] * CAP + pos] = t;
                wgt[id[k] * CAP + pos] = wk;
            }
            res[t * NK + k] = (id[k] << 16) | (pos & 0xffff);
            rw[t * NK + k] = wk;
        }
    }
}

// ---------------- mlp1: h = swiglu(t @ w1[e]^T + b1) * route_w ----------------
// Persistent-strip streaming: 512 blocks (2/CU), each owns 128 contiguous
// w1-rows (512 KiB) of one expert, walked as 8 tiles of 16 rows x K=1024.
// Double-buffered LDS (2 x 32 KiB bf16, XOR-swizzled). Next tile's weights
// prefetched into regs (nontemporal) before the K-loop. B gathered from
// L2-resident tbf with depth-2 register prefetch. Branch-free over slots.
__global__ __launch_bounds__(512, 4) void k_mlp1(
    const float* __restrict__ w1, const float* __restrict__ b1,
    const __bf16* __restrict__ tbf, const int* __restrict__ cnt,
    const int* __restrict__ tok, const float* __restrict__ wgt,
    __bf16* __restrict__ h)
{
    const int b   = blockIdx.x;          // 512 blocks
    const int tid = threadIdx.x;
    const int e       = b >> 4;          // 16 blocks per expert
    const int rowbase = (b & 15) * 128;  // 8 tiles x 16 rows

    __shared__ __bf16 A[2][16 * 1024];   // 2 x 32 KiB

    const int lane = tid & 63, wv = tid >> 6;
    const int mr = lane & 15, qd = lane >> 4;
    const int aswz = (mr & 7) << 4;
    const int aoff = mr * 2048 + ((qd * 16) ^ (aswz & 0x30));
    const int offE = aoff + (aswz & 0x40);
    const int offO = aoff + (64 - (aswz & 0x40));

    const int slot0 = wv * 32 + mr;      // 8 waves x 32 slots = 256
    const int slot1 = slot0 + 16;
    const int tk0 = tok[e * CAP + slot0];
    const int tk1 = tok[e * CAP + slot1];
    const float wt0 = wgt[e * CAP + slot0];
    const float wt1 = wgt[e * CAP + slot1];
    const __bf16* bp0 = tbf + (size_t)tk0 * HH + qd * 8;
    const __bf16* bp1 = tbf + (size_t)tk1 * HH + qd * 8;

    const float* abase = w1 + ((size_t)e * 2048 + rowbase) * HH;

    f32x4v av[8];
    #pragma unroll
    for (int i = 0; i < 8; ++i)
        av[i] = __builtin_nontemporal_load(&((const f32x4v*)abase)[i * 512 + tid]);

    for (int t = 0; t < 8; ++t) {
        __bf16* Ab = A[t & 1];
        // convert + swizzled ds_write of tile t (waits its own loads only)
        #pragma unroll
        for (int i = 0; i < 8; ++i) {
            const int fi = i * 512 + tid;
            const int row = fi >> 8, c4 = fi & 255;
            bf16x4 pv = { (__bf16)av[i][0], (__bf16)av[i][1],
                          (__bf16)av[i][2], (__bf16)av[i][3] };
            *(bf16x4*)((char*)Ab + row * 2048 + ((c4 * 8) ^ ((row & 7) << 4))) = pv;
        }
        __syncthreads();
        // issue next tile's stream (nt) before compute
        if (t < 7) {
            const f32x4v* src = (const f32x4v*)(abase + (size_t)(t + 1) * 16 * HH);
            #pragma unroll
            for (int i = 0; i < 8; ++i)
                av[i] = __builtin_nontemporal_load(&src[i * 512 + tid]);
        }

        f32x4v acc0 = {0.f, 0.f, 0.f, 0.f};
        f32x4v acc1 = {0.f, 0.f, 0.f, 0.f};

        bf16x8 P[2][4];
        #pragma unroll
        for (int j = 0; j < 2; ++j) {
            P[j][0] = *(const bf16x8*)(bp0 + (2 * j)     * 32);
            P[j][1] = *(const bf16x8*)(bp1 + (2 * j)     * 32);
            P[j][2] = *(const bf16x8*)(bp0 + (2 * j + 1) * 32);
            P[j][3] = *(const bf16x8*)(bp1 + (2 * j + 1) * 32);
        }
        #pragma unroll
        for (int kk = 0; kk < 16; ++kk) {
            bf16x8 N0, N1, N2, N3;
            if (kk < 14) {
                N0 = *(const bf16x8*)(bp0 + (2 * kk + 4) * 32);
                N1 = *(const bf16x8*)(bp1 + (2 * kk + 4) * 32);
                N2 = *(const bf16x8*)(bp0 + (2 * kk + 5) * 32);
                N3 = *(const bf16x8*)(bp1 + (2 * kk + 5) * 32);
            }
            const bf16x8 a0 = *(const bf16x8*)((const char*)Ab + offE + kk * 128);
            acc0 = __builtin_amdgcn_mfma_f32_16x16x32_bf16(a0, P[kk & 1][0], acc0, 0, 0, 0);
            acc1 = __builtin_amdgcn_mfma_f32_16x16x32_bf16(a0, P[kk & 1][1], acc1, 0, 0, 0);
            const bf16x8 a1 = *(const bf16x8*)((const char*)Ab + offO + kk * 128);
            acc0 = __builtin_amdgcn_mfma_f32_16x16x32_bf16(a1, P[kk & 1][2], acc0, 0, 0, 0);
            acc1 = __builtin_amdgcn_mfma_f32_16x16x32_bf16(a1, P[kk & 1][3], acc1, 0, 0, 0);
            if (kk < 14) { P[kk & 1][0] = N0; P[kk & 1][1] = N1;
                           P[kk & 1][2] = N2; P[kk & 1][3] = N3; }
        }

        // epilogue: bias + swiglu + route weight (wt=0 for dead slots)
        const int rowb = rowbase + t * 16 + qd * 4;   // absolute w1-row (even)
        const float4 bv = *(const float4*)(b1 + e * 2048 + rowb);
        {
            float g0 = acc0[0] + bv.x, l0 = acc0[1] + bv.y;
            float g1 = acc0[2] + bv.z, l1 = acc0[3] + bv.w;
            g0 = fminf(g0, 7.f); g1 = fminf(g1, 7.f);
            l0 = fminf(fmaxf(l0, -7.f), 7.f); l1 = fminf(fmaxf(l1, -7.f), 7.f);
            const float h0 = g0 * (1.f / (1.f + __expf(-1.702f * g0))) * (l0 + 1.f) * wt0;
            const float h1 = g1 * (1.f / (1.f + __expf(-1.702f * g1))) * (l1 + 1.f) * wt0;
            bf16x2 hv = { (__bf16)h0, (__bf16)h1 };
            *(bf16x2*)(h + ((size_t)e * CAP + slot0) * FF + (rowb >> 1)) = hv;
        }
        {
            float g0 = acc1[0] + bv.x, l0 = acc1[1] + bv.y;
            float g1 = acc1[2] + bv.z, l1 = acc1[3] + bv.w;
            g0 = fminf(g0, 7.f); g1 = fminf(g1, 7.f);
            l0 = fminf(fmaxf(l0, -7.f), 7.f); l1 = fminf(fmaxf(l1, -7.f), 7.f);
            const float h0 = g0 * (1.f / (1.f + __expf(-1.702f * g0))) * (l0 + 1.f) * wt1;
            const float h1 = g1 * (1.f / (1.f + __expf(-1.702f * g1))) * (l1 + 1.f) * wt1;
            bf16x2 hv = { (__bf16)h0, (__bf16)h1 };
            *(bf16x2*)(h + ((size_t)e * CAP + slot1) * FF + (rowb >> 1)) = hv;
        }
    }
}

// ---------------- mlp2: h2[e,slot,:] = h[e,slot,:] @ w2[e]^T ----------------
__global__ __launch_bounds__(512, 4) void k_mlp2(
    const float* __restrict__ w2, const __bf16* __restrict__ h,
    const int* __restrict__ cnt, __bf16* __restrict__ h2)
{
    const int b   = blockIdx.x;          // 512 blocks
    const int tid = threadIdx.x;
    const int e       = b >> 4;
    const int colbase = (b & 15) * 64;   // 4 tiles x 16 cols

    __shared__ __bf16 A[2][16 * 1024];   // 2 x 32 KiB

    const int lane = tid & 63, wv = tid >> 6;
    const int mr = lane & 15, qd = lane >> 4;
    const int aswz = (mr & 7) << 4;
    const int aoff = mr * 2048 + ((qd * 16) ^ (aswz & 0x30));
    const int offE = aoff + (aswz & 0x40);
    const int offO = aoff + (64 - (aswz & 0x40));

    const int slot0 = wv * 32 + mr;
    const int slot1 = slot0 + 16;
    const __bf16* bp0 = h + ((size_t)e * CAP + slot0) * FF + qd * 8;
    const __bf16* bp1 = h + ((size_t)e * CAP + slot1) * FF + qd * 8;

    const float* abase = w2 + ((size_t)e * HH + colbase) * FF;

    f32x4v av[8];
    #pragma unroll
    for (int i = 0; i < 8; ++i)
        av[i] = __builtin_nontemporal_load(&((const f32x4v*)abase)[i * 512 + tid]);

    for (int t = 0; t < 4; ++t) {
        __bf16* Ab = A[t & 1];
        #pragma unroll
        for (int i = 0; i < 8; ++i) {
            const int fi = i * 512 + tid;
            const int row = fi >> 8, c4 = fi & 255;
            bf16x4 pv = { (__bf16)av[i][0], (__bf16)av[i][1],
                          (__bf16)av[i][2], (__bf16)av[i][3] };
            *(bf16x4*)((char*)Ab + row * 2048 + ((c4 * 8) ^ ((row & 7) << 4))) = pv;
        }
        __syncthreads();
        if (t < 3) {
            const f32x4v* src = (const f32x4v*)(abase + (size_t)(t + 1) * 16 * FF);
            #pragma unroll
            for (int i = 0; i < 8; ++i)
                av[i] = __builtin_nontemporal_load(&src[i * 512 + tid]);
        }

        f32x4v acc0 = {0.f, 0.f, 0.f, 0.f};
        f32x4v acc1 = {0.f, 0.f, 0.f, 0.f};

        bf16x8 P[2][4];
        #pragma unroll
        for (int j = 0; j < 2; ++j) {
            P[j][0] = *(const bf16x8*)(bp0 + (2 * j)     * 32);
            P[j][1] = *(const bf16x8*)(bp1 + (2 * j)     * 32);
            P[j][2] = *(const bf16x8*)(bp0 + (2 * j + 1) * 32);
            P[j][3] = *(const bf16x8*)(bp1 + (2 * j + 1) * 32);
        }
        #pragma unroll
        for (int kk = 0; kk < 16; ++kk) {
            bf16x8 N0, N1, N2, N3;
            if (kk < 14) {
                N0 = *(const bf16x8*)(bp0 + (2 * kk + 4) * 32);
                N1 = *(const bf16x8*)(bp1 + (2 * kk + 4) * 32);
                N2 = *(const bf16x8*)(bp0 + (2 * kk + 5) * 32);
                N3 = *(const bf16x8*)(bp1 + (2 * kk + 5) * 32);
            }
            const bf16x8 a0 = *(const bf16x8*)((const char*)Ab + offE + kk * 128);
            acc0 = __builtin_amdgcn_mfma_f32_16x16x32_bf16(a0, P[kk & 1][0], acc0, 0, 0, 0);
            acc1 = __builtin_amdgcn_mfma_f32_16x16x32_bf16(a0, P[kk & 1][1], acc1, 0, 0, 0);
            const bf16x8 a1 = *(const bf16x8*)((const char*)Ab + offO + kk * 128);
            acc0 = __builtin_amdgcn_mfma_f32_16x16x32_bf16(a1, P[kk & 1][2], acc0, 0, 0, 0);
            acc1 = __builtin_amdgcn_mfma_f32_16x16x32_bf16(a1, P[kk & 1][3], acc1, 0, 0, 0);
            if (kk < 14) { P[kk & 1][0] = N0; P[kk & 1][1] = N1;
                           P[kk & 1][2] = N2; P[kk & 1][3] = N3; }
        }

        const int colb = colbase + t * 16 + qd * 4;
        {
            bf16x4 ov = { (__bf16)acc0[0], (__bf16)acc0[1],
                          (__bf16)acc0[2], (__bf16)acc0[3] };
            *(bf16x4*)&h2[((size_t)e * CAP + slot0) * HH + colb] = ov;
        }
        {
            bf16x4 ov = { (__bf16)acc1[0], (__bf16)acc1[1],
                          (__bf16)acc1[2], (__bf16)acc1[3] };
            *(bf16x4*)&h2[((size_t)e * CAP + slot1) * HH + colb] = ov;
        }
    }
}

// ---------------- combine: out = x + sum_k (h2[e_k,pos_k,:] + w_k*b2[e_k,:]) ----------------
__global__ __launch_bounds__(256) void k_combine(
    const float* __restrict__ x, const float* __restrict__ b2,
    const __bf16* __restrict__ h2, const int* __restrict__ res,
    const float* __restrict__ rw, float* __restrict__ out)
{
    const int t = blockIdx.x, tid = threadIdx.x;
    float4 acc = ((const float4*)(x + (size_t)t * HH))[tid];
    #pragma unroll
    for (int k = 0; k < NK; ++k) {
        const int es = res[t * NK + k];
        const float wt = rw[t * NK + k];
        const int e = es >> 16, pos = es & 0xffff;
        if (pos < CAP) {
            bf16x4 hv = *(const bf16x4*)(h2 + ((size_t)e * CAP + pos) * HH + tid * 4);
            float4 bv = ((const float4*)(b2 + (size_t)e * HH))[tid];
            acc.x += (float)hv[0] + wt * bv.x;
            acc.y += (float)hv[1] + wt * bv.y;
            acc.z += (float)hv[2] + wt * bv.z;
            acc.w += (float)hv[3] + wt * bv.w;
        }
    }
    ((float4*)(out + (size_t)t * HH))[tid] = acc;
}

extern "C" void kernel_launch(void* const* d_in, const int* in_sizes, int n_in,
                              void* d_out, int out_size, void* d_ws, size_t ws_size,
                              hipStream_t stream) {
    const float* x      = (const float*)d_in[0];
    const float* nscale = (const float*)d_in[1];
    const float* gw     = (const float*)d_in[2];
    const float* gb     = (const float*)d_in[3];
    const float* w1     = (const float*)d_in[4];
    const float* b1     = (const float*)d_in[5];
    const float* w2     = (const float*)d_in[6];
    const float* b2     = (const float*)d_in[7];
    float* out = (float*)d_out;

    char* ws = (char*)d_ws;
    int*    cnt = (int*)(ws);
    int*    tok = (int*)(ws + OFF_TOK);
    float*  wgt = (float*)(ws + OFF_WGT);
    int*    res = (int*)(ws + OFF_ES);
    float*  rw  = (float*)(ws + OFF_RW);
    __bf16* tbf = (__bf16*)(ws + OFF_T);
    __bf16* h   = (__bf16*)(ws + OFF_H);
    __bf16* h2  = (__bf16*)(ws + OFF_H2);

    k_zero<<<32, 256, 0, stream>>>(cnt, tok, wgt);
    k_router<<<1024, 256, 0, stream>>>(x, nscale, gw, gb, tbf, cnt, tok, wgt, res, rw);
    k_mlp1<<<512, 512, 0, stream>>>(w1, b1, tbf, cnt, tok, wgt, h);
    k_mlp2<<<512, 512, 0, stream>>>(w2, h, cnt, h2);
    k_combine<<<1024, 256, 0, stream>>>(x, b2, h2, res, rw, out);
}